// Round 1
// baseline (276.223 us; speedup 1.0000x reference)
//
#include <hip/hip_runtime.h>

// SSIM over 64 independent 512x512 slices, 11x11 uniform window (separable box),
// zero padding, output = 1 - mean(ssim_map).

constexpr int IMG = 512;
constexpr int TW  = 64;           // output tile width
constexpr int TH  = 32;           // output tile height
constexpr int HW_ = TW + 10;      // halo width  = 74
constexpr int HH_ = TH + 10;      // halo height = 42
constexpr int LST = 77;           // LDS row stride (77 % 32 = 13 -> conflict-free)
constexpr float WSCALE = 1.0f / 121.0f;
constexpr float C1F = 0.0001f;    // 0.01^2
constexpr float C2F = 0.0009f;    // 0.03^2

template <bool ATOMIC>
__global__ __launch_bounds__(256) void ssim_main(const float* __restrict__ x,
                                                 const float* __restrict__ y,
                                                 float* __restrict__ out_ws) {
  __shared__ float rawx[HH_ * LST];
  __shared__ float rawy[HH_ * LST];
  __shared__ float cs[5 * TH * LST];   // column sums: sx, sy, sxx, syy, sxy
  __shared__ float wsum[4];

  const int tid  = threadIdx.x;
  const int col0 = blockIdx.x * TW - 5;
  const int row0 = blockIdx.y * TH - 5;
  const size_t base = (size_t)blockIdx.z * (IMG * IMG);

  // ---- Phase A: stage halo tiles of x, y into LDS (zero-padded) ----
  for (int i = tid; i < HH_ * HW_; i += 256) {
    const int r = i / HW_;
    const int c = i - r * HW_;
    const int gr = row0 + r;
    const int gc = col0 + c;
    float vx = 0.0f, vy = 0.0f;
    if ((unsigned)gr < (unsigned)IMG && (unsigned)gc < (unsigned)IMG) {
      const size_t idx = base + (size_t)gr * IMG + gc;
      vx = x[idx];
      vy = y[idx];
    }
    rawx[r * LST + c] = vx;
    rawy[r * LST + c] = vy;
  }
  __syncthreads();

  // ---- Phase B: vertical 11-row running sums of 5 quantities ----
  // tasks: 4 chunks of 8 output rows x 74 columns = 296 tasks
  for (int task = tid; task < 4 * HW_; task += 256) {
    const int c  = task % HW_;
    const int ch = task / HW_;
    const int r0 = ch * 8;

    float sx = 0.f, sy = 0.f, sxx = 0.f, syy = 0.f, sxy = 0.f;
    #pragma unroll
    for (int k = 0; k < 11; ++k) {
      const float xv = rawx[(r0 + k) * LST + c];
      const float yv = rawy[(r0 + k) * LST + c];
      sx += xv; sy += yv;
      sxx += xv * xv; syy += yv * yv; sxy += xv * yv;
    }
    #pragma unroll
    for (int r = 0; r < 8; ++r) {
      const int o = (r0 + r) * LST + c;
      cs[0 * TH * LST + o] = sx;
      cs[1 * TH * LST + o] = sy;
      cs[2 * TH * LST + o] = sxx;
      cs[3 * TH * LST + o] = syy;
      cs[4 * TH * LST + o] = sxy;
      if (r < 7) {
        const float xn = rawx[(r0 + r + 11) * LST + c];
        const float yn = rawy[(r0 + r + 11) * LST + c];
        const float xo = rawx[(r0 + r) * LST + c];
        const float yo = rawy[(r0 + r) * LST + c];
        sx  += xn - xo;
        sy  += yn - yo;
        sxx += xn * xn - xo * xo;
        syy += yn * yn - yo * yo;
        sxy += xn * yn - xo * yo;
      }
    }
  }
  __syncthreads();

  // ---- Phase C: horizontal 11-col running sums + SSIM + reduce ----
  // thread -> (row r = tid>>3, col group of 8 = (tid&7)*8); exactly 256 tasks
  const int r  = tid >> 3;
  const int c0 = (tid & 7) * 8;
  const int rowbase = r * LST;

  float s0 = 0.f, s1 = 0.f, s2 = 0.f, s3 = 0.f, s4 = 0.f;
  #pragma unroll
  for (int k = 0; k < 11; ++k) {
    const int o = rowbase + c0 + k;
    s0 += cs[0 * TH * LST + o];
    s1 += cs[1 * TH * LST + o];
    s2 += cs[2 * TH * LST + o];
    s3 += cs[3 * TH * LST + o];
    s4 += cs[4 * TH * LST + o];
  }

  float acc = 0.f;
  #pragma unroll
  for (int j = 0; j < 8; ++j) {
    const float mu_x = s0 * WSCALE;
    const float mu_y = s1 * WSCALE;
    const float e_x2 = s2 * WSCALE;
    const float e_y2 = s3 * WSCALE;
    const float e_xy = s4 * WSCALE;
    const float mu_x_sq = mu_x * mu_x;
    const float mu_y_sq = mu_y * mu_y;
    const float mu_xy   = mu_x * mu_y;
    const float sig_x  = e_x2 - mu_x_sq;
    const float sig_y  = e_y2 - mu_y_sq;
    const float sig_xy = e_xy - mu_xy;
    const float num = fmaf(2.f, mu_xy, C1F) * fmaf(2.f, sig_xy, C2F);
    const float den = (mu_x_sq + mu_y_sq + C1F) * (sig_x + sig_y + C2F);
    acc += num / den;

    if (j < 7) {
      const int on = rowbase + c0 + j + 11;
      const int oo = rowbase + c0 + j;
      s0 += cs[0 * TH * LST + on] - cs[0 * TH * LST + oo];
      s1 += cs[1 * TH * LST + on] - cs[1 * TH * LST + oo];
      s2 += cs[2 * TH * LST + on] - cs[2 * TH * LST + oo];
      s3 += cs[3 * TH * LST + on] - cs[3 * TH * LST + oo];
      s4 += cs[4 * TH * LST + on] - cs[4 * TH * LST + oo];
    }
  }

  // block reduction: wave shuffle then cross-wave via LDS
  #pragma unroll
  for (int off = 32; off > 0; off >>= 1) acc += __shfl_down(acc, off, 64);
  if ((tid & 63) == 0) wsum[tid >> 6] = acc;
  __syncthreads();
  if (tid == 0) {
    const float t = wsum[0] + wsum[1] + wsum[2] + wsum[3];
    if (ATOMIC) {
      atomicAdd(out_ws, t);
    } else {
      out_ws[(blockIdx.z * gridDim.y + blockIdx.y) * gridDim.x + blockIdx.x] = t;
    }
  }
}

__global__ void ssim_finalize(const float* __restrict__ partials, int n,
                              float* __restrict__ out) {
  __shared__ float wsum[4];
  float acc = 0.f;
  for (int i = threadIdx.x; i < n; i += 256) acc += partials[i];
  #pragma unroll
  for (int off = 32; off > 0; off >>= 1) acc += __shfl_down(acc, off, 64);
  if ((threadIdx.x & 63) == 0) wsum[threadIdx.x >> 6] = acc;
  __syncthreads();
  if (threadIdx.x == 0) {
    const float t = wsum[0] + wsum[1] + wsum[2] + wsum[3];
    out[0] = 1.0f - t * (1.0f / (64.0f * 512.0f * 512.0f));
  }
}

__global__ void ssim_zero(float* p) {
  if (threadIdx.x == 0) p[0] = 0.f;
}

__global__ void ssim_finalize_atomic(const float* __restrict__ accp,
                                     float* __restrict__ out) {
  if (threadIdx.x == 0)
    out[0] = 1.0f - accp[0] * (1.0f / (64.0f * 512.0f * 512.0f));
}

extern "C" void kernel_launch(void* const* d_in, const int* in_sizes, int n_in,
                              void* d_out, int out_size, void* d_ws, size_t ws_size,
                              hipStream_t stream) {
  const float* x = (const float*)d_in[0];
  const float* y = (const float*)d_in[1];
  // d_in[2] is the window; by construction uniform 1/121 -> folded into WSCALE.
  float* out = (float*)d_out;

  dim3 grid(IMG / TW, IMG / TH, 64);   // (8, 16, 64) = 8192 blocks
  dim3 block(256);
  const int nblocks = (IMG / TW) * (IMG / TH) * 64;

  if (ws_size >= (size_t)nblocks * sizeof(float)) {
    float* partials = (float*)d_ws;
    ssim_main<false><<<grid, block, 0, stream>>>(x, y, partials);
    ssim_finalize<<<1, 256, 0, stream>>>(partials, nblocks, out);
  } else {
    float* accp = (float*)d_ws;   // single-float accumulator fallback
    ssim_zero<<<1, 64, 0, stream>>>(accp);
    ssim_main<true><<<grid, block, 0, stream>>>(x, y, accp);
    ssim_finalize_atomic<<<1, 64, 0, stream>>>(accp, out);
  }
}

// Round 3
// 184.364 us; speedup vs baseline: 1.4982x; 1.4982x over previous
//
#include <hip/hip_runtime.h>

// SSIM, 64 slices of 512x512, 11x11 uniform window (separable box), zero pad.
// Streaming design: block = one row-band of one slice, full 512-col width.
//  - vertical running box sums in registers (thread owns 2 cols); the
//    "subtract row r-11" values are re-loaded from global (L2-hot).
//  - 4 rows of column sums exchanged via a small LDS slab (41.9 KB),
//    XOR-swizzled so the stride-8 horizontal reads are conflict-free.
//  - horizontal running box sums: 1 wave per row, 8 output cols per thread.
// R3 fix: subtract-row reload guard must also exclude gro >= IMG (rows >= 512
// entered the running sums as zeros); unguarded read past the array was the
// R2 page-fault/abort.

constexpr int IMG    = 512;
constexpr int OUT_R  = 22;                        // output rows per block
constexpr int CHUNKS = (IMG + OUT_R - 1) / OUT_R; // 24
constexpr int ITERS  = (OUT_R + 10) / 4;          // 8 iterations x 4 rows
constexpr int PW     = 524;                       // slab row width (words)
constexpr int PLANE  = 4 * PW;                    // 4 row-slots per quantity
constexpr float WSCALE = 1.0f / 121.0f;
constexpr float C1F = 1e-4f;                      // 0.01^2
constexpr float C2F = 9e-4f;                      // 0.03^2

// XOR swizzle on word index: flips bits 1..2 by 32-group. Keeps even pairs
// adjacent + 8B-aligned; spreads the stride-8-col read pattern over all 16
// bank-pairs (b64 accesses land 4 lanes/bank-pair = conflict-free).
__device__ __forceinline__ int sidx(int c) {
  return c ^ (((c >> 5) & 3) << 1);
}

template <bool ATOMIC>
__global__ __launch_bounds__(256, 3) void ssim_main(const float* __restrict__ x,
                                                    const float* __restrict__ y,
                                                    float* __restrict__ out_ws) {
  __shared__ float slab[5 * PLANE];   // 5 quantities x 4 row-slots x 524 words
  __shared__ float wsum[4];

  const int tid   = threadIdx.x;
  const int chunk = blockIdx.x;
  const int z     = blockIdx.y;
  const int O0    = chunk * OUT_R;    // first output row of this block
  const int r0    = O0 - 5;           // first streamed input row
  const float* xs = x + (size_t)z * IMG * IMG;
  const float* ys = y + (size_t)z * IMG * IMG;

  // Zero the horizontal pad columns (cols -6..-1 and 512..517 -> c 0..5, 518..523).
  // Never written by the vertical phase; first __syncthreads orders vs reads.
  if (tid < 240) {
    const int q  = tid / 48;
    const int rj = (tid % 48) / 12;
    const int ci = tid % 12;
    const int c  = (ci < 6) ? ci : (518 + ci - 6);
    slab[q * PLANE + rj * PW + sidx(c)] = 0.f;
  }

  // vertical running sums for the thread's two columns (c0, c0+1)
  const int c0 = 2 * tid;
  float sX0 = 0.f, sX1 = 0.f, sY0 = 0.f, sY1 = 0.f;
  float sXX0 = 0.f, sXX1 = 0.f, sYY0 = 0.f, sYY1 = 0.f, sXY0 = 0.f, sXY1 = 0.f;

  // write address (column-sum slab), col index shifted by +6
  const int wb = sidx(c0 + 6);

  // horizontal phase: wave jrow handles row-slot jrow, thread group g owns
  // output cols 8g..8g+7; needs cols 8g-5..8g+12 -> slab c in [8g+1, 8g+18],
  // read as 10 aligned float2 covering c in [8g, 8g+19].
  const int g    = tid & 63;
  const int jrow = tid >> 6;
  int ra[10];
#pragma unroll
  for (int m = 0; m < 10; ++m) ra[m] = jrow * PW + sidx(8 * g + 2 * m);

  float acc = 0.f;

  for (int k = 0; k < ITERS; ++k) {
    // ---- vertical: 4 input rows, update running sums, write column sums ----
#pragma unroll
    for (int j = 0; j < 4; ++j) {
      const int gr = r0 + 4 * k + j;
      float2 xn = make_float2(0.f, 0.f), yn = make_float2(0.f, 0.f);
      float2 xo = make_float2(0.f, 0.f), yo = make_float2(0.f, 0.f);
      if ((unsigned)gr < (unsigned)IMG) {
        xn = *(const float2*)(xs + (size_t)gr * IMG + c0);
        yn = *(const float2*)(ys + (size_t)gr * IMG + c0);
      }
      const int gro = gr - 11;   // row leaving the window (re-load: L2-hot)
      if (gro >= r0 && (unsigned)gro < (unsigned)IMG) {
        xo = *(const float2*)(xs + (size_t)gro * IMG + c0);
        yo = *(const float2*)(ys + (size_t)gro * IMG + c0);
      }
      sX0  += xn.x - xo.x;               sX1  += xn.y - xo.y;
      sY0  += yn.x - yo.x;               sY1  += yn.y - yo.y;
      sXX0 += xn.x * xn.x - xo.x * xo.x; sXX1 += xn.y * xn.y - xo.y * xo.y;
      sYY0 += yn.x * yn.x - yo.x * yo.x; sYY1 += yn.y * yn.y - yo.y * yo.y;
      sXY0 += xn.x * yn.x - xo.x * yo.x; sXY1 += xn.y * yn.y - xo.y * yo.y;

      *(float2*)&slab[0 * PLANE + j * PW + wb] = make_float2(sX0, sX1);
      *(float2*)&slab[1 * PLANE + j * PW + wb] = make_float2(sY0, sY1);
      *(float2*)&slab[2 * PLANE + j * PW + wb] = make_float2(sXX0, sXX1);
      *(float2*)&slab[3 * PLANE + j * PW + wb] = make_float2(sYY0, sYY1);
      *(float2*)&slab[4 * PLANE + j * PW + wb] = make_float2(sXY0, sXY1);
    }
    __syncthreads();

    // ---- horizontal: wave per row-slot, 8 outputs per thread ----
    const int iw   = 4 * k + jrow;      // stream index of this wave's row
    const int orow = O0 + iw - 10;      // output row it produces
    if (iw >= 10 && orow < IMG) {
      float b[5][8];
#pragma unroll
      for (int q = 0; q < 5; ++q) {
        float v[20];
#pragma unroll
        for (int m = 0; m < 10; ++m) {
          const float2 t = *(const float2*)&slab[q * PLANE + ra[m]];
          v[2 * m] = t.x; v[2 * m + 1] = t.y;
        }
        float s = v[1];
#pragma unroll
        for (int k2 = 2; k2 <= 11; ++k2) s += v[k2];
        b[q][0] = s;
#pragma unroll
        for (int j2 = 1; j2 < 8; ++j2) { s += v[j2 + 11] - v[j2]; b[q][j2] = s; }
      }
#pragma unroll
      for (int j2 = 0; j2 < 8; ++j2) {
        const float mu_x = b[0][j2] * WSCALE;
        const float mu_y = b[1][j2] * WSCALE;
        const float ex2  = b[2][j2] * WSCALE;
        const float ey2  = b[3][j2] * WSCALE;
        const float exy  = b[4][j2] * WSCALE;
        const float mxx = mu_x * mu_x;
        const float myy = mu_y * mu_y;
        const float mxy = mu_x * mu_y;
        const float num = fmaf(2.f, mxy, C1F) * fmaf(2.f, exy - mxy, C2F);
        const float den = (mxx + myy + C1F) * ((ex2 - mxx) + (ey2 - myy) + C2F);
        acc += num * __builtin_amdgcn_rcpf(den);
      }
    }
    __syncthreads();   // slab reused next iteration
  }

  // ---- block reduction ----
#pragma unroll
  for (int off = 32; off > 0; off >>= 1) acc += __shfl_down(acc, off, 64);
  if ((tid & 63) == 0) wsum[tid >> 6] = acc;
  __syncthreads();
  if (tid == 0) {
    const float t = wsum[0] + wsum[1] + wsum[2] + wsum[3];
    if (ATOMIC) {
      atomicAdd(out_ws, t);
    } else {
      out_ws[blockIdx.y * CHUNKS + blockIdx.x] = t;
    }
  }
}

__global__ void ssim_finalize(const float* __restrict__ partials, int n,
                              float* __restrict__ out) {
  __shared__ float wsum[4];
  float acc = 0.f;
  for (int i = threadIdx.x; i < n; i += 256) acc += partials[i];
#pragma unroll
  for (int off = 32; off > 0; off >>= 1) acc += __shfl_down(acc, off, 64);
  if ((threadIdx.x & 63) == 0) wsum[threadIdx.x >> 6] = acc;
  __syncthreads();
  if (threadIdx.x == 0) {
    const float t = wsum[0] + wsum[1] + wsum[2] + wsum[3];
    out[0] = 1.0f - t * (1.0f / (64.0f * 512.0f * 512.0f));
  }
}

__global__ void ssim_zero(float* p) {
  if (threadIdx.x == 0) p[0] = 0.f;
}

__global__ void ssim_finalize_atomic(const float* __restrict__ accp,
                                     float* __restrict__ out) {
  if (threadIdx.x == 0)
    out[0] = 1.0f - accp[0] * (1.0f / (64.0f * 512.0f * 512.0f));
}

extern "C" void kernel_launch(void* const* d_in, const int* in_sizes, int n_in,
                              void* d_out, int out_size, void* d_ws, size_t ws_size,
                              hipStream_t stream) {
  const float* x = (const float*)d_in[0];
  const float* y = (const float*)d_in[1];
  // d_in[2]: uniform 1/121 window, folded into WSCALE.
  float* out = (float*)d_out;

  dim3 grid(CHUNKS, 64);    // 24 x 64 = 1536 blocks
  dim3 block(256);
  const int nblocks = CHUNKS * 64;

  if (ws_size >= (size_t)nblocks * sizeof(float)) {
    float* partials = (float*)d_ws;
    ssim_main<false><<<grid, block, 0, stream>>>(x, y, partials);
    ssim_finalize<<<1, 256, 0, stream>>>(partials, nblocks, out);
  } else {
    float* accp = (float*)d_ws;
    ssim_zero<<<1, 64, 0, stream>>>(accp);
    ssim_main<true><<<grid, block, 0, stream>>>(x, y, accp);
    ssim_finalize_atomic<<<1, 64, 0, stream>>>(accp, out);
  }
}